// Round 18
// baseline (69.311 us; speedup 1.0000x reference)
//
#include <hip/hip_runtime.h>

// HopfRNNCellTheta: T=64 < UNITS=1024 -> z[:,0] stays 0 -> A unused,
// y_t = 0.5*(B@x_t). Output = REAL part only, float32[64][1024][1024].
// out[t][n][u] = ReY[s][n], s = t+u-1023, if s>=0 else 0.
//
// r18 = r17 with the compile fix: __builtin_nontemporal_store requires a
// native ext_vector type, not HIP's float4 class -> use f4v. Theory
// unchanged: nt stores stop the 256 MB fill stream from evicting xT/B out
// of per-XCD L2 during the gemv phase (32 MB of xT re-reads stay L2-hits).

#define NDIM 1024

typedef _Float16 half2_t __attribute__((ext_vector_type(2)));
typedef float f4v __attribute__((ext_vector_type(4)));

__device__ __forceinline__ unsigned pk_f16(float a, float b) {
  return __builtin_bit_cast(unsigned, __builtin_amdgcn_cvt_pkrtz(a, b));
}
__device__ __forceinline__ half2_t bc2(unsigned u) {
  return __builtin_bit_cast(half2_t, u);
}

// zero-prefix of row r = (t,n): words [0,Z) zero, word Z comps [0,k) zero.
// Z = (1023-t)>>2 in [240,256), k = (1023-t)&3. Band cells untouched.
__device__ __forceinline__ void fill_rows(float* __restrict__ out, int rstart,
                                          int rcount, int rlimit, int lane) {
  const f4v z = {0.f, 0.f, 0.f, 0.f};
  int rend = rstart + rcount;
  if (rend > rlimit) rend = rlimit;
  for (int r = rstart; r < rend; ++r) {
    const int t = r >> 10;
    const int n = r & 1023;
    const int rem = 1023 - t;
    const int Z = rem >> 2;
    const int k = rem & 3;
    f4v* rp = (f4v*)out + ((long long)t << 18) + (n << 8);
    __builtin_nontemporal_store(z, &rp[lane]);        // lanes 0..63 (<240<=Z)
    __builtin_nontemporal_store(z, &rp[lane + 64]);
    __builtin_nontemporal_store(z, &rp[lane + 128]);
    if (lane + 192 < Z) __builtin_nontemporal_store(z, &rp[lane + 192]);
    if (lane < k) __builtin_nontemporal_store(0.f, &((float*)(rp + Z))[lane]);
  }
}

// ---- K0: 16 transpose+pack blocks + 240 fill blocks ----
__global__ __launch_bounds__(256) void k0_transpose_fill(
    const float* __restrict__ x_re, const float* __restrict__ x_im,
    unsigned* __restrict__ xTh, float* __restrict__ out) {
  __shared__ float s1[64][65];
  __shared__ float s2[64][65];
  const int tid = threadIdx.x;
  if (blockIdx.x >= 16) {
    const int kw = (int)(blockIdx.x - 16) * 4 + (tid >> 6);  // 0..959
    fill_rows(out, 59776 + kw * 6, 6, 65536, tid & 63);
    return;
  }
  const int m0 = blockIdx.x * 64;
#pragma unroll
  for (int k = 0; k < 16; ++k) {           // coalesced reads
    const int s = tid + k * 256;
    const int tr = s >> 6, j = s & 63;
    s1[tr][j] = x_re[tr * NDIM + m0 + j];
    s2[tr][j] = x_im[tr * NDIM + m0 + j];
  }
  __syncthreads();
#pragma unroll
  for (int k = 0; k < 16; ++k) {           // coalesced writes, CF LDS reads
    const int s = tid + k * 256;
    const int ml = s >> 6, t = s & 63;
    // f16 pair (xr, -xi): dot2 with (br, bi) gives br*xr - bi*xi directly
    xTh[(m0 + ml) * 64 + t] = pk_f16(s1[t][ml], -s2[t][ml]);
  }
}

// ---- K1: fused gemv + row-structured zero-fill ----
__global__ __launch_bounds__(256) void hopf_fused10(
    const unsigned* __restrict__ xTh,
    const float* __restrict__ B_re, const float* __restrict__ B_im,
    float* __restrict__ out) {
  __shared__ unsigned bs[4][8][256];   // [wave][row][m'] packed (br,bi) f16
  __shared__ float red[4][8][64];      // [k-wave][row][t]
  const int tid = threadIdx.x;
  const int t = tid & 63;
  const int w = tid >> 6;

  if (blockIdx.x >= 128) {
    const int gfw = (int)(blockIdx.x - 128) * 4 + w;   // 0..3583
    fill_rows(out, gfw * 16, 16, 57344, t);
    return;
  }

  // ---------- gemv: block rows nb..nb+7; wave w reduces m-quarter w ----------
  __builtin_amdgcn_s_setprio(1);
  const int nb = blockIdx.x * 8;
  const int mbase = w << 8;

  // stage B[nb+r][mbase..mbase+256) packed f16 into wave-private LDS
  // (no barrier: same-wave ds_write->ds_read ordered by compiler lgkmcnt)
#pragma unroll
  for (int r = 0; r < 8; ++r) {
    const float4 re = *(const float4*)(B_re + (nb + r) * NDIM + mbase + t * 4);
    const float4 im = *(const float4*)(B_im + (nb + r) * NDIM + mbase + t * 4);
    uint4 pk;
    pk.x = pk_f16(re.x, im.x);
    pk.y = pk_f16(re.y, im.y);
    pk.z = pk_f16(re.z, im.z);
    pk.w = pk_f16(re.w, im.w);
    *(uint4*)&bs[w][r][t * 4] = pk;
  }

  float acc0 = 0.f, acc1 = 0.f, acc2 = 0.f, acc3 = 0.f;
  float acc4 = 0.f, acc5 = 0.f, acc6 = 0.f, acc7 = 0.f;
  const unsigned* xp = xTh + (mbase << 6) + t;
  unsigned xv[16], xn[16];

#define ROWDOT(R, BQ)                                                   \
  do {                                                                  \
    acc##R = __builtin_amdgcn_fdot2(bc2(BQ.x), x0, acc##R, false);      \
    acc##R = __builtin_amdgcn_fdot2(bc2(BQ.y), x1, acc##R, false);      \
    acc##R = __builtin_amdgcn_fdot2(bc2(BQ.z), x2, acc##R, false);      \
    acc##R = __builtin_amdgcn_fdot2(bc2(BQ.w), x3, acc##R, false);      \
  } while (0)

#define COMP(X, MB)                                                     \
  do {                                                                  \
    _Pragma("unroll")                                                   \
    for (int q = 0; q < 4; ++q) {                                       \
      const half2_t x0 = bc2(X[q * 4 + 0]);                             \
      const half2_t x1 = bc2(X[q * 4 + 1]);                             \
      const half2_t x2 = bc2(X[q * 4 + 2]);                             \
      const half2_t x3 = bc2(X[q * 4 + 3]);                             \
      const uint4 b0 = *(const uint4*)&bs[w][0][(MB) + q * 4];          \
      ROWDOT(0, b0);                                                    \
      const uint4 b1 = *(const uint4*)&bs[w][1][(MB) + q * 4];          \
      ROWDOT(1, b1);                                                    \
      const uint4 b2 = *(const uint4*)&bs[w][2][(MB) + q * 4];          \
      ROWDOT(2, b2);                                                    \
      const uint4 b3 = *(const uint4*)&bs[w][3][(MB) + q * 4];          \
      ROWDOT(3, b3);                                                    \
      const uint4 b4 = *(const uint4*)&bs[w][4][(MB) + q * 4];          \
      ROWDOT(4, b4);                                                    \
      const uint4 b5 = *(const uint4*)&bs[w][5][(MB) + q * 4];          \
      ROWDOT(5, b5);                                                    \
      const uint4 b6 = *(const uint4*)&bs[w][6][(MB) + q * 4];          \
      ROWDOT(6, b6);                                                    \
      const uint4 b7 = *(const uint4*)&bs[w][7][(MB) + q * 4];          \
      ROWDOT(7, b7);                                                    \
    }                                                                   \
  } while (0)

#pragma unroll
  for (int j = 0; j < 16; ++j) xv[j] = xp[j * 64];   // chunk 0 in flight

#pragma unroll 1
  for (int m0 = 0; m0 < 256; m0 += 32) {
#pragma unroll
    for (int j = 0; j < 16; ++j) xn[j] = xp[(m0 + 16 + j) * 64];
    COMP(xv, m0);
    if (m0 + 32 < 256) {
#pragma unroll
      for (int j = 0; j < 16; ++j) xv[j] = xp[(m0 + 32 + j) * 64];
    }
    COMP(xn, m0 + 16);
  }

  // ---------- cross-wave K-reduce ----------
  red[w][0][t] = acc0;
  red[w][1][t] = acc1;
  red[w][2][t] = acc2;
  red[w][3][t] = acc3;
  red[w][4][t] = acc4;
  red[w][5][t] = acc5;
  red[w][6][t] = acc6;
  red[w][7][t] = acc7;
  __syncthreads();
  // wave w owns rows nb+w and nb+w+4
  const float yv0 =
      0.5f * (red[0][w][t] + red[1][w][t] + red[2][w][t] + red[3][w][t]);
  const int w4 = w + 4;
  const float yv1 =
      0.5f * (red[0][w4][t] + red[1][w4][t] + red[2][w4][t] + red[3][w4][t]);

  // ---------- band write: wave-uniform tt -> coalesced bursts ----------
  const long long ro0 = (long long)(nb + w) << 10;
  const long long ro1 = (long long)(nb + w4) << 10;
  for (int tt = 0; tt < 64; ++tt) {
    if (t <= tt) {
      const long long po = ((long long)tt << 20) + (1023 - tt) + t;
      __builtin_nontemporal_store(yv0, &out[po + ro0]);
      __builtin_nontemporal_store(yv1, &out[po + ro1]);
    }
  }

  // ---------- static post-gemv fill share ----------
  __builtin_amdgcn_s_setprio(0);
  const int gid = blockIdx.x * 4 + w;      // 0..511
  fill_rows(out, 57344 + gid * 5, 5, 59776, t);
}

// ---- fallback (round-6 fused, known-passing; used only if ws too small) ----
__global__ __launch_bounds__(256) void hopf_fused_fb(
    const float* __restrict__ x_re, const float* __restrict__ x_im,
    const float* __restrict__ B_re, const float* __restrict__ B_im,
    float* __restrict__ out) {
  __shared__ float s1[64][65];
  __shared__ float s2[64][65];
  const int tid = threadIdx.x;
  if (blockIdx.x >= 256) {
    float4* out4 = (float4*)out;
    const float4 z = make_float4(0.f, 0.f, 0.f, 0.f);
    const int stride = 768 * 256;
    for (int q = (int)(blockIdx.x - 256) * 256 + tid; q < (1 << 24);
         q += stride) {
      const int t = q >> 18;
      const int u4 = q & 255;
      const int sb = t + 4 * u4 - 1023;
      if (sb <= -4) {
        out4[q] = z;
      } else if (sb < 0) {
        float* p = out + ((long long)q << 2);
        p[0] = 0.f;
        if (sb + 1 < 0) p[1] = 0.f;
        if (sb + 2 < 0) p[2] = 0.f;
      }
    }
    return;
  }
  const int t = tid & 63;
  const int ng = tid >> 6;
  const int n = blockIdx.x * 4 + ng;
  const float* p1 = B_re + n * NDIM;
  const float* p2 = B_im + n * NDIM;
  float a1 = 0.f, a2 = 0.f;
  for (int m0 = 0; m0 < NDIM; m0 += 64) {
    __syncthreads();
#pragma unroll
    for (int k = 0; k < 16; ++k) {
      const int s = tid + k * 256;
      const int tr2 = s >> 6, j = s & 63;
      s1[tr2][j] = x_re[tr2 * NDIM + m0 + j];
      s2[tr2][j] = x_im[tr2 * NDIM + m0 + j];
    }
    __syncthreads();
#pragma unroll 16
    for (int mm = 0; mm < 64; ++mm) {
      a1 = fmaf(p1[m0 + mm], s1[t][mm], a1);
      a2 = fmaf(p2[m0 + mm], s2[t][mm], a2);
    }
  }
  const float yv = 0.5f * (a1 - a2);
  const long long rowoff = (long long)(n << 10);
  for (int tt = 0; tt < 64; ++tt) {
    if (t <= tt) {
      out[((long long)tt << 20) + rowoff + (1023 - tt) + t] = yv;
    }
  }
}

extern "C" void kernel_launch(void* const* d_in, const int* in_sizes, int n_in,
                              void* d_out, int out_size, void* d_ws, size_t ws_size,
                              hipStream_t stream) {
  (void)in_sizes; (void)n_in; (void)out_size;
  const float* x_re = (const float*)d_in[0];
  const float* x_im = (const float*)d_in[1];
  const float* B_re = (const float*)d_in[4];
  const float* B_im = (const float*)d_in[5];
  float* out = (float*)d_out;

  if (ws_size >= (size_t)(NDIM * 64 * sizeof(unsigned))) {
    unsigned* xTh = (unsigned*)d_ws;   // [1024 m][64 t] packed f16 (xr,-xi)
    k0_transpose_fill<<<256, 256, 0, stream>>>(x_re, x_im, xTh, out);
    hopf_fused10<<<1024, 256, 0, stream>>>(xTh, B_re, B_im, out);
  } else {
    hopf_fused_fb<<<1024, 256, 0, stream>>>(x_re, x_im, B_re, B_im, out);
  }
}

// Round 19
// 43.601 us; speedup vs baseline: 1.5897x; 1.5897x over previous
//
#include <hip/hip_runtime.h>

// HopfRNNCellTheta: T=64 < UNITS=1024 -> z[:,0] stays 0 -> A unused,
// y_t = 0.5*(B@x_t). Output = REAL part only, float32[64][1024][1024].
// out[t][n][u] = ReY[s][n], s = t+u-1023, if s>=0 else 0.
//
// r19 = r16 verbatim (best known: 44.2us). r17/r18's non-temporal stores
// REGRESSED to 69us: gfx950 'nt' stores bypass the efficient L2
// write-combining path (-35% fill throughput). Structure: K0 = 16
// transpose+f16-pack blocks + 240 fill blocks; K1 = 128 gemv blocks
// (f16 dot2, 8 rows/block, wave-private LDS B, no barriers in loop,
// ping-pong xT prefetch, then coalesced band write + small fill share)
// + 896 row-structured fill blocks (~1.3 instr/word, BW-bound).

#define NDIM 1024

typedef _Float16 half2_t __attribute__((ext_vector_type(2)));

__device__ __forceinline__ unsigned pk_f16(float a, float b) {
  return __builtin_bit_cast(unsigned, __builtin_amdgcn_cvt_pkrtz(a, b));
}
__device__ __forceinline__ half2_t bc2(unsigned u) {
  return __builtin_bit_cast(half2_t, u);
}

// zero-prefix of row r = (t,n): words [0,Z) zero, word Z comps [0,k) zero.
// Z = (1023-t)>>2 in [240,256), k = (1023-t)&3. Band cells untouched.
__device__ __forceinline__ void fill_rows(float* __restrict__ out, int rstart,
                                          int rcount, int rlimit, int lane) {
  const float4 z = make_float4(0.f, 0.f, 0.f, 0.f);
  int rend = rstart + rcount;
  if (rend > rlimit) rend = rlimit;
  for (int r = rstart; r < rend; ++r) {
    const int t = r >> 10;
    const int n = r & 1023;
    const int rem = 1023 - t;
    const int Z = rem >> 2;
    const int k = rem & 3;
    float4* rp = (float4*)out + ((long long)t << 18) + (n << 8);
    rp[lane] = z;                          // lanes 0..63  (< 240 <= Z)
    rp[lane + 64] = z;
    rp[lane + 128] = z;
    if (lane + 192 < Z) rp[lane + 192] = z;
    if (lane < k) ((float*)(rp + Z))[lane] = 0.f;
  }
}

// ---- K0: 16 transpose+pack blocks + 240 fill blocks ----
__global__ __launch_bounds__(256) void k0_transpose_fill(
    const float* __restrict__ x_re, const float* __restrict__ x_im,
    unsigned* __restrict__ xTh, float* __restrict__ out) {
  __shared__ float s1[64][65];
  __shared__ float s2[64][65];
  const int tid = threadIdx.x;
  if (blockIdx.x >= 16) {
    const int kw = (int)(blockIdx.x - 16) * 4 + (tid >> 6);  // 0..959
    fill_rows(out, 59776 + kw * 6, 6, 65536, tid & 63);
    return;
  }
  const int m0 = blockIdx.x * 64;
#pragma unroll
  for (int k = 0; k < 16; ++k) {           // coalesced reads
    const int s = tid + k * 256;
    const int tr = s >> 6, j = s & 63;
    s1[tr][j] = x_re[tr * NDIM + m0 + j];
    s2[tr][j] = x_im[tr * NDIM + m0 + j];
  }
  __syncthreads();
#pragma unroll
  for (int k = 0; k < 16; ++k) {           // coalesced writes, CF LDS reads
    const int s = tid + k * 256;
    const int ml = s >> 6, t = s & 63;
    // f16 pair (xr, -xi): dot2 with (br, bi) gives br*xr - bi*xi directly
    xTh[(m0 + ml) * 64 + t] = pk_f16(s1[t][ml], -s2[t][ml]);
  }
}

// ---- K1: fused gemv + row-structured zero-fill ----
__global__ __launch_bounds__(256) void hopf_fused9(
    const unsigned* __restrict__ xTh,
    const float* __restrict__ B_re, const float* __restrict__ B_im,
    float* __restrict__ out) {
  __shared__ unsigned bs[4][8][256];   // [wave][row][m'] packed (br,bi) f16
  __shared__ float red[4][8][64];      // [k-wave][row][t]
  const int tid = threadIdx.x;
  const int t = tid & 63;
  const int w = tid >> 6;

  if (blockIdx.x >= 128) {
    const int gfw = (int)(blockIdx.x - 128) * 4 + w;   // 0..3583
    fill_rows(out, gfw * 16, 16, 57344, t);
    return;
  }

  // ---------- gemv: block rows nb..nb+7; wave w reduces m-quarter w ----------
  __builtin_amdgcn_s_setprio(1);
  const int nb = blockIdx.x * 8;
  const int mbase = w << 8;

  // stage B[nb+r][mbase..mbase+256) packed f16 into wave-private LDS
  // (no barrier: same-wave ds_write->ds_read ordered by compiler lgkmcnt)
#pragma unroll
  for (int r = 0; r < 8; ++r) {
    const float4 re = *(const float4*)(B_re + (nb + r) * NDIM + mbase + t * 4);
    const float4 im = *(const float4*)(B_im + (nb + r) * NDIM + mbase + t * 4);
    uint4 pk;
    pk.x = pk_f16(re.x, im.x);
    pk.y = pk_f16(re.y, im.y);
    pk.z = pk_f16(re.z, im.z);
    pk.w = pk_f16(re.w, im.w);
    *(uint4*)&bs[w][r][t * 4] = pk;
  }

  float acc0 = 0.f, acc1 = 0.f, acc2 = 0.f, acc3 = 0.f;
  float acc4 = 0.f, acc5 = 0.f, acc6 = 0.f, acc7 = 0.f;
  const unsigned* xp = xTh + (mbase << 6) + t;
  unsigned xv[16], xn[16];

#define ROWDOT(R, BQ)                                                   \
  do {                                                                  \
    acc##R = __builtin_amdgcn_fdot2(bc2(BQ.x), x0, acc##R, false);      \
    acc##R = __builtin_amdgcn_fdot2(bc2(BQ.y), x1, acc##R, false);      \
    acc##R = __builtin_amdgcn_fdot2(bc2(BQ.z), x2, acc##R, false);      \
    acc##R = __builtin_amdgcn_fdot2(bc2(BQ.w), x3, acc##R, false);      \
  } while (0)

#define COMP(X, MB)                                                     \
  do {                                                                  \
    _Pragma("unroll")                                                   \
    for (int q = 0; q < 4; ++q) {                                       \
      const half2_t x0 = bc2(X[q * 4 + 0]);                             \
      const half2_t x1 = bc2(X[q * 4 + 1]);                             \
      const half2_t x2 = bc2(X[q * 4 + 2]);                             \
      const half2_t x3 = bc2(X[q * 4 + 3]);                             \
      const uint4 b0 = *(const uint4*)&bs[w][0][(MB) + q * 4];          \
      ROWDOT(0, b0);                                                    \
      const uint4 b1 = *(const uint4*)&bs[w][1][(MB) + q * 4];          \
      ROWDOT(1, b1);                                                    \
      const uint4 b2 = *(const uint4*)&bs[w][2][(MB) + q * 4];          \
      ROWDOT(2, b2);                                                    \
      const uint4 b3 = *(const uint4*)&bs[w][3][(MB) + q * 4];          \
      ROWDOT(3, b3);                                                    \
      const uint4 b4 = *(const uint4*)&bs[w][4][(MB) + q * 4];          \
      ROWDOT(4, b4);                                                    \
      const uint4 b5 = *(const uint4*)&bs[w][5][(MB) + q * 4];          \
      ROWDOT(5, b5);                                                    \
      const uint4 b6 = *(const uint4*)&bs[w][6][(MB) + q * 4];          \
      ROWDOT(6, b6);                                                    \
      const uint4 b7 = *(const uint4*)&bs[w][7][(MB) + q * 4];          \
      ROWDOT(7, b7);                                                    \
    }                                                                   \
  } while (0)

#pragma unroll
  for (int j = 0; j < 16; ++j) xv[j] = xp[j * 64];   // chunk 0 in flight

#pragma unroll 1
  for (int m0 = 0; m0 < 256; m0 += 32) {
#pragma unroll
    for (int j = 0; j < 16; ++j) xn[j] = xp[(m0 + 16 + j) * 64];
    COMP(xv, m0);
    if (m0 + 32 < 256) {
#pragma unroll
      for (int j = 0; j < 16; ++j) xv[j] = xp[(m0 + 32 + j) * 64];
    }
    COMP(xn, m0 + 16);
  }

  // ---------- cross-wave K-reduce ----------
  red[w][0][t] = acc0;
  red[w][1][t] = acc1;
  red[w][2][t] = acc2;
  red[w][3][t] = acc3;
  red[w][4][t] = acc4;
  red[w][5][t] = acc5;
  red[w][6][t] = acc6;
  red[w][7][t] = acc7;
  __syncthreads();
  // wave w owns rows nb+w and nb+w+4
  const float yv0 =
      0.5f * (red[0][w][t] + red[1][w][t] + red[2][w][t] + red[3][w][t]);
  const int w4 = w + 4;
  const float yv1 =
      0.5f * (red[0][w4][t] + red[1][w4][t] + red[2][w4][t] + red[3][w4][t]);

  // ---------- band write: wave-uniform tt -> coalesced bursts ----------
  const long long ro0 = (long long)(nb + w) << 10;
  const long long ro1 = (long long)(nb + w4) << 10;
  for (int tt = 0; tt < 64; ++tt) {
    if (t <= tt) {
      const long long po = ((long long)tt << 20) + (1023 - tt) + t;
      out[po + ro0] = yv0;
      out[po + ro1] = yv1;
    }
  }

  // ---------- static post-gemv fill share ----------
  __builtin_amdgcn_s_setprio(0);
  const int gid = blockIdx.x * 4 + w;      // 0..511
  fill_rows(out, 57344 + gid * 5, 5, 59776, t);
}

// ---- fallback (round-6 fused, known-passing; used only if ws too small) ----
__global__ __launch_bounds__(256) void hopf_fused_fb(
    const float* __restrict__ x_re, const float* __restrict__ x_im,
    const float* __restrict__ B_re, const float* __restrict__ B_im,
    float* __restrict__ out) {
  __shared__ float s1[64][65];
  __shared__ float s2[64][65];
  const int tid = threadIdx.x;
  if (blockIdx.x >= 256) {
    float4* out4 = (float4*)out;
    const float4 z = make_float4(0.f, 0.f, 0.f, 0.f);
    const int stride = 768 * 256;
    for (int q = (int)(blockIdx.x - 256) * 256 + tid; q < (1 << 24);
         q += stride) {
      const int t = q >> 18;
      const int u4 = q & 255;
      const int sb = t + 4 * u4 - 1023;
      if (sb <= -4) {
        out4[q] = z;
      } else if (sb < 0) {
        float* p = out + ((long long)q << 2);
        p[0] = 0.f;
        if (sb + 1 < 0) p[1] = 0.f;
        if (sb + 2 < 0) p[2] = 0.f;
      }
    }
    return;
  }
  const int t = tid & 63;
  const int ng = tid >> 6;
  const int n = blockIdx.x * 4 + ng;
  const float* p1 = B_re + n * NDIM;
  const float* p2 = B_im + n * NDIM;
  float a1 = 0.f, a2 = 0.f;
  for (int m0 = 0; m0 < NDIM; m0 += 64) {
    __syncthreads();
#pragma unroll
    for (int k = 0; k < 16; ++k) {
      const int s = tid + k * 256;
      const int tr2 = s >> 6, j = s & 63;
      s1[tr2][j] = x_re[tr2 * NDIM + m0 + j];
      s2[tr2][j] = x_im[tr2 * NDIM + m0 + j];
    }
    __syncthreads();
#pragma unroll 16
    for (int mm = 0; mm < 64; ++mm) {
      a1 = fmaf(p1[m0 + mm], s1[t][mm], a1);
      a2 = fmaf(p2[m0 + mm], s2[t][mm], a2);
    }
  }
  const float yv = 0.5f * (a1 - a2);
  const long long rowoff = (long long)(n << 10);
  for (int tt = 0; tt < 64; ++tt) {
    if (t <= tt) {
      out[((long long)tt << 20) + rowoff + (1023 - tt) + t] = yv;
    }
  }
}

extern "C" void kernel_launch(void* const* d_in, const int* in_sizes, int n_in,
                              void* d_out, int out_size, void* d_ws, size_t ws_size,
                              hipStream_t stream) {
  (void)in_sizes; (void)n_in; (void)out_size;
  const float* x_re = (const float*)d_in[0];
  const float* x_im = (const float*)d_in[1];
  const float* B_re = (const float*)d_in[4];
  const float* B_im = (const float*)d_in[5];
  float* out = (float*)d_out;

  if (ws_size >= (size_t)(NDIM * 64 * sizeof(unsigned))) {
    unsigned* xTh = (unsigned*)d_ws;   // [1024 m][64 t] packed f16 (xr,-xi)
    k0_transpose_fill<<<256, 256, 0, stream>>>(x_re, x_im, xTh, out);
    hopf_fused9<<<1024, 256, 0, stream>>>(xTh, B_re, B_im, out);
  } else {
    hopf_fused_fb<<<1024, 256, 0, stream>>>(x_re, x_im, B_re, B_im, out);
  }
}